// Round 9
// baseline (267.542 us; speedup 1.0000x reference)
//
#include <hip/hip_runtime.h>
#include <hip/hip_bf16.h>
#include <stdint.h>

typedef __bf16 bf16;
typedef __bf16 bf16x4 __attribute__((ext_vector_type(4)));
typedef __bf16 bf16x8 __attribute__((ext_vector_type(8)));
typedef float  f32x4  __attribute__((ext_vector_type(4)));
typedef short  s16x4  __attribute__((ext_vector_type(4)));

#define NB 2
#define NS 2048
#define NE 1024
#define NH 16
#define ND 64
#define NC 256

// async global->LDS, 16B per lane, wave-uniform LDS base + lane*16
__device__ __forceinline__ void gload16(void* lds, const void* g) {
  __builtin_amdgcn_global_load_lds(
      (const __attribute__((address_space(1))) void*)g,
      (__attribute__((address_space(3))) void*)lds, 16, 0, 0);
}

// 16x16x16 bf16 MFMA (K=16): A,B = 4 bf16 (2 VGPRs) each
__device__ __forceinline__ f32x4 mfma16(bf16x4 a, bf16x4 b, f32x4 c) {
#if __has_builtin(__builtin_amdgcn_mfma_f32_16x16x16_bf16)
  return __builtin_amdgcn_mfma_f32_16x16x16_bf16(a, b, c, 0, 0, 0);
#elif __has_builtin(__builtin_amdgcn_mfma_f32_16x16x16bf16_1k)
  return __builtin_amdgcn_mfma_f32_16x16x16bf16_1k(
      __builtin_bit_cast(s16x4, a), __builtin_bit_cast(s16x4, b), c, 0, 0, 0);
#else
  f32x4 d = c;
  asm volatile("v_mfma_f32_16x16x16_bf16 %0, %1, %2, %0"
               : "+v"(d) : "v"(a), "v"(b));
  return d;
#endif
}

// ---------------------------------------------------------------------------
// f32 -> bf16 conversion (vectorized, 8 elems/thread)
// ---------------------------------------------------------------------------
__global__ __launch_bounds__(256) void cvt_kernel(
    const float* __restrict__ src, bf16* __restrict__ dst, int n) {
  int i = (blockIdx.x * 256 + threadIdx.x) * 8;
  if (i >= n) return;
  float4 a = ((const float4*)(src + i))[0];
  float4 b = ((const float4*)(src + i))[1];
  bf16x8 o;
  o[0] = (bf16)a.x; o[1] = (bf16)a.y; o[2] = (bf16)a.z; o[3] = (bf16)a.w;
  o[4] = (bf16)b.x; o[5] = (bf16)b.y; o[6] = (bf16)b.z; o[7] = (bf16)b.w;
  *(bf16x8*)(dst + i) = o;
}

// fused conversion of the four 1024x1024 weights into one contiguous dst
__global__ __launch_bounds__(256) void cvt4_kernel(
    const float* __restrict__ s0, const float* __restrict__ s1,
    const float* __restrict__ s2, const float* __restrict__ s3,
    bf16* __restrict__ dst) {
  int seg = blockIdx.x >> 9;
  int blk = blockIdx.x & 511;
  const float* s = (seg == 0) ? s0 : (seg == 1) ? s1 : (seg == 2) ? s2 : s3;
  int i = (blk * 256 + threadIdx.x) * 8;
  float4 a = ((const float4*)(s + i))[0];
  float4 b = ((const float4*)(s + i))[1];
  bf16x8 o;
  o[0] = (bf16)a.x; o[1] = (bf16)a.y; o[2] = (bf16)a.z; o[3] = (bf16)a.w;
  o[4] = (bf16)b.x; o[5] = (bf16)b.y; o[6] = (bf16)b.z; o[7] = (bf16)b.w;
  *(bf16x8*)(dst + seg * 1048576 + i) = o;
}

// ---------------------------------------------------------------------------
// mod = silu(conditioning) @ Wc^T + bc   -> f32 (B, 2E)
// ---------------------------------------------------------------------------
__global__ __launch_bounds__(256) void mod_kernel(
    const float* __restrict__ cond, const float* __restrict__ Wc,
    const float* __restrict__ bc, float* __restrict__ mod) {
  __shared__ float scond[NC];
  int b  = blockIdx.x >> 3;
  int j0 = (blockIdx.x & 7) * 256;
  float c = cond[b * NC + threadIdx.x];
  scond[threadIdx.x] = c / (1.f + __expf(-c));
  __syncthreads();
  int j = j0 + threadIdx.x;
  float acc = bc[j];
  const float* wrow = Wc + (size_t)j * NC;
  for (int cc = 0; cc < NC; ++cc) acc += scond[cc] * wrow[cc];
  mod[b * 2 * NE + j] = acc;
}

// ---------------------------------------------------------------------------
// 128x128 LDS-staged NT GEMM (m97 structure). K multiple of 32.
// MODE 0: fused QKV (N=3072, weight picked by n>>10), scatter epilogue.
// MODE 1: O-projection, f32 row-major out, N=1024.
// ---------------------------------------------------------------------------
template<int MODE>
__global__ __launch_bounds__(256) void gemm128(
    const bf16* __restrict__ A, const bf16* __restrict__ W0,
    const bf16* __restrict__ W1, const bf16* __restrict__ W2,
    void* __restrict__ out, int K) {
  __shared__ bf16 As[128 * 32];
  __shared__ bf16 Bs[128 * 32];
  const int t = threadIdx.x, w = t >> 6, l = t & 63;
  const int lr = l & 15, lg = l >> 4;
  const int wm = w >> 1, wn = w & 1;
  const int m0 = blockIdx.x * 128;
  const int ng = blockIdx.y * 128;

  const bf16* Bw;
  if (MODE == 0) {
    const bf16* Ws[3] = {W0, W1, W2};
    Bw = Ws[ng >> 10] + (size_t)(ng & 1023) * K;
  } else {
    Bw = W0 + (size_t)ng * K;
  }

  f32x4 acc[4][4];
#pragma unroll
  for (int i = 0; i < 4; ++i)
#pragma unroll
    for (int j = 0; j < 4; ++j) acc[i][j] = (f32x4){0.f, 0.f, 0.f, 0.f};

  const int srow = (l >> 2);
  const int scol = (l & 3) * 8;

  for (int kt = 0; kt < K; kt += 32) {
#pragma unroll
    for (int r = 0; r < 2; ++r) {
      int cc = w * 2 + r;
      int row = cc * 16 + srow;
      gload16((char*)As + cc * 1024, A  + (size_t)(m0 + row) * K + kt + scol);
      gload16((char*)Bs + cc * 1024, Bw + (size_t)row        * K + kt + scol);
    }
    __syncthreads();
    bf16x8 af[4], bfr[4];
#pragma unroll
    for (int i = 0; i < 4; ++i) {
      af[i]  = *(const bf16x8*)(As + (wm * 64 + i * 16 + lr) * 32 + lg * 8);
      bfr[i] = *(const bf16x8*)(Bs + (wn * 64 + i * 16 + lr) * 32 + lg * 8);
    }
#pragma unroll
    for (int i = 0; i < 4; ++i)
#pragma unroll
      for (int j = 0; j < 4; ++j)
        acc[i][j] = __builtin_amdgcn_mfma_f32_16x16x32_bf16(af[i], bfr[j], acc[i][j], 0, 0, 0);
    if (kt + 32 < K) __syncthreads();
  }

#pragma unroll
  for (int i = 0; i < 4; ++i) {
#pragma unroll
    for (int j = 0; j < 4; ++j) {
#pragma unroll
      for (int r = 0; r < 4; ++r) {
        int row = m0 + wm * 64 + i * 16 + lg * 4 + r;
        int col = ng + wn * 64 + j * 16 + lr;
        float v = acc[i][j][r];
        if (MODE == 1) {
          ((float*)out)[(size_t)row * NE + col] = v;
        } else {
          int b = row >> 11, s = row & 2047;
          int wi = col >> 10, nc = col & 1023;
          int h = nc >> 6, d = nc & 63;
          size_t idx;
          if (wi == 2)  // V^T: (B,H,D,S)
            idx = 8388608u + (((size_t)(b * NH + h)) * ND + d) * NS + s;
          else          // Q or K: (B,H,S,D)
            idx = (size_t)wi * 4194304u + (((size_t)(b * NH + h)) * NS + s) * ND + d;
          ((bf16*)out)[idx] = (bf16)v;
        }
      }
    }
  }
}

// ---------------------------------------------------------------------------
// Flash attention, causal, swapped-operand, KV-split x4 + XCD swizzle.
// Q,K (B,H,S,D), V^T (B,H,D,S). Out (B,S,E) bf16.
// Block = 4 waves on ONE complementary q-pair (tp, 127-tp); wave w takes
// kv-iters {w, w+4, ...}. S^T = mfma(K,Q): P-row lane-local; no LDS in the
// loop. 4-way merge of (m, l, O^T) through an 18KB LDS slab, per tile.
// Grid 2048 blocks; bid&7 = XCD -> 4 heads/XCD (2MB K/V in 4MB L2).
// Masked-out partials carry m=-1e30 -> merge factor exp2(m-ms)=0 kills them.
// ---------------------------------------------------------------------------
__global__ __launch_bounds__(256, 4) void attn_kernel(
    const bf16* __restrict__ Q, const bf16* __restrict__ Km,
    const bf16* __restrict__ Vt, bf16* __restrict__ O) {
  __shared__ float smrg[4][18][64];   // [wave][m | l | 16 o-rows][lane]
  const int l = threadIdx.x & 63, w = threadIdx.x >> 6;
  const int lr = l & 15, lg = l >> 4;
  const int bid = blockIdx.x;
  const int xcd = bid & 7, slot = bid >> 3;       // slot 0..255
  const int bh = xcd * 4 + (slot >> 6);
  const int b = bh >> 4, h = bh & 15;
  const int tp = slot & 63;                       // 0..63
  const int qb0 = tp * 16;                        // small tile
  const int qb1 = (127 - tp) * 16;                // large tile

  const bf16* Qb = Q  + (size_t)bh * NS * ND;
  const bf16* Kb = Km + (size_t)bh * NS * ND;
  const bf16* Vb = Vt + (size_t)bh * ND * NS;

  const float c = 0.125f * 1.44269504089f;   // scale * log2(e)

  bf16x8 qf00 = *(const bf16x8*)(Qb + (size_t)(qb0 + lr) * ND + lg * 8);
  bf16x8 qf01 = *(const bf16x8*)(Qb + (size_t)(qb0 + lr) * ND + 32 + lg * 8);
  bf16x8 qf10 = *(const bf16x8*)(Qb + (size_t)(qb1 + lr) * ND + lg * 8);
  bf16x8 qf11 = *(const bf16x8*)(Qb + (size_t)(qb1 + lr) * ND + 32 + lg * 8);

  f32x4 ot0[4], ot1[4];
#pragma unroll
  for (int dt = 0; dt < 4; ++dt) {
    ot0[dt] = (f32x4){0.f, 0.f, 0.f, 0.f};
    ot1[dt] = (f32x4){0.f, 0.f, 0.f, 0.f};
  }
  float m0 = -1e30f, m1 = -1e30f, ls0 = 0.f, ls1 = 0.f;

  const int n0 = (qb0 + 16 + 63) >> 6;
  const int n1 = (qb1 + 16 + 63) >> 6;

  for (int it = w; it < n1; it += 4) {
    const int kv0 = it * 64;
    bf16x8 k0[4], k1[4];
#pragma unroll
    for (int nt = 0; nt < 4; ++nt) {
      const bf16* kr = Kb + (size_t)(kv0 + nt * 16 + lr) * ND + lg * 8;
      k0[nt] = *(const bf16x8*)kr;
      k1[nt] = *(const bf16x8*)(kr + 32);
    }
    bf16x4 vf[4][4];
#pragma unroll
    for (int dt = 0; dt < 4; ++dt)
#pragma unroll
      for (int nt = 0; nt < 4; ++nt)
        vf[dt][nt] = *(const bf16x4*)(Vb + (size_t)(dt * 16 + lr) * NS + kv0 + nt * 16 + lg * 4);

    auto proc = [&](int qbase, float& m, float& ls, f32x4 (&ot)[4],
                    const bf16x8& qfa, const bf16x8& qfb) {
      f32x4 s[4];
#pragma unroll
      for (int nt = 0; nt < 4; ++nt) {
        f32x4 z = (f32x4){0.f, 0.f, 0.f, 0.f};
        z = __builtin_amdgcn_mfma_f32_16x16x32_bf16(k0[nt], qfa, z, 0, 0, 0);
        z = __builtin_amdgcn_mfma_f32_16x16x32_bf16(k1[nt], qfb, z, 0, 0, 0);
        s[nt] = z;   // S^T: lane = (q=qbase+lr), kv = kv0+nt*16+lg*4+r
      }
      const int qi = qbase + lr;
      const bool edge = (kv0 + 63 > qbase);
      float pm = -1e30f;
#pragma unroll
      for (int nt = 0; nt < 4; ++nt) {
        f32x4 v = s[nt] * c;
        if (edge) {
#pragma unroll
          for (int r = 0; r < 4; ++r)
            if (kv0 + nt * 16 + lg * 4 + r > qi) v[r] = -1e30f;
        }
#pragma unroll
        for (int r = 0; r < 4; ++r) pm = fmaxf(pm, v[r]);
        s[nt] = v;
      }
      pm = fmaxf(pm, __shfl_xor(pm, 16, 64));
      pm = fmaxf(pm, __shfl_xor(pm, 32, 64));
      float nm = fmaxf(m, pm);
      float al = exp2f(m - nm);
      m = nm;
      ls *= al;
#pragma unroll
      for (int dt = 0; dt < 4; ++dt) ot[dt] *= al;
      bf16x4 pf[4];
#pragma unroll
      for (int nt = 0; nt < 4; ++nt) {
#pragma unroll
        for (int r = 0; r < 4; ++r) {
          float p = exp2f(s[nt][r] - m);
          ls += p;
          pf[nt][r] = (bf16)p;
        }
      }
#pragma unroll
      for (int dt = 0; dt < 4; ++dt)
#pragma unroll
        for (int nt = 0; nt < 4; ++nt)
          ot[dt] = mfma16(vf[dt][nt], pf[nt], ot[dt]);
    };

    if (it < n0) proc(qb0, m0, ls0, ot0, qf00, qf01);
    proc(qb1, m1, ls1, ot1, qf10, qf11);
  }

  // ---- 4-way merge per tile through LDS; wave w owns d-tile dt = w ----
  auto merge_store = [&](int qbase, float m, float ls, f32x4 (&ot)[4]) {
    ls += __shfl_xor(ls, 16, 64);
    ls += __shfl_xor(ls, 32, 64);
    float* my = &smrg[w][0][0];
    my[l] = m;
    my[64 + l] = ls;
#pragma unroll
    for (int dt = 0; dt < 4; ++dt)
#pragma unroll
      for (int r = 0; r < 4; ++r) my[(2 + dt * 4 + r) * 64 + l] = ot[dt][r];
    __syncthreads();
    float mv[4];
#pragma unroll
    for (int ww = 0; ww < 4; ++ww) mv[ww] = smrg[ww][0][l];
    float ms = fmaxf(fmaxf(mv[0], mv[1]), fmaxf(mv[2], mv[3]));
    float osM = 0.f, oM[4] = {0.f, 0.f, 0.f, 0.f};
#pragma unroll
    for (int ww = 0; ww < 4; ++ww) {
      float sf = exp2f(mv[ww] - ms);
      osM += sf * smrg[ww][1][l];
#pragma unroll
      for (int r = 0; r < 4; ++r) oM[r] += sf * smrg[ww][2 + w * 4 + r][l];
    }
    float rl = 1.f / osM;
    bf16x4 ov;
#pragma unroll
    for (int r = 0; r < 4; ++r) ov[r] = (bf16)(oM[r] * rl);
    *(bf16x4*)&O[((size_t)(b * NS) + qbase + lr) * NE + h * ND + w * 16 + lg * 4] = ov;
  };

  merge_store(qb0, m0, ls0, ot0);
  __syncthreads();
  merge_store(qb1, m1, ls1, ot1);
}

// ---------------------------------------------------------------------------
// RMSNorm + FiLM
// ---------------------------------------------------------------------------
__global__ __launch_bounds__(256) void norm_kernel(
    const float* __restrict__ tmp, const float* __restrict__ rms_scale,
    const float* __restrict__ mod, float* __restrict__ out) {
  int row = blockIdx.x;
  int b = row >> 11;
  const float* trow = tmp + (size_t)row * NE;
  float4 v = ((const float4*)trow)[threadIdx.x];
  float vv[4] = {v.x, v.y, v.z, v.w};
  float ss = vv[0]*vv[0] + vv[1]*vv[1] + vv[2]*vv[2] + vv[3]*vv[3];
#pragma unroll
  for (int mk = 1; mk < 64; mk <<= 1) ss += __shfl_xor(ss, mk, 64);
  __shared__ float sred[4];
  if ((threadIdx.x & 63) == 0) sred[threadIdx.x >> 6] = ss;
  __syncthreads();
  float tot = sred[0] + sred[1] + sred[2] + sred[3];
  float rinv = rsqrtf(tot * (1.f / NE) + 1e-6f);
  const float* modb = mod + b * 2 * NE;
#pragma unroll
  for (int j = 0; j < 4; ++j) {
    int e = threadIdx.x * 4 + j;
    float xn = vv[j] * rinv * rms_scale[e];
    xn = xn * (1.f + modb[NE + e]) + modb[e];
    out[(size_t)row * NE + e] = xn;
  }
}

// ---------------------------------------------------------------------------
extern "C" void kernel_launch(void* const* d_in, const int* in_sizes, int n_in,
                              void* d_out, int out_size, void* d_ws, size_t ws_size,
                              hipStream_t stream) {
  const float* x    = (const float*)d_in[0];
  const float* cond = (const float*)d_in[2];
  const float* Wq   = (const float*)d_in[3];
  const float* Wk   = (const float*)d_in[4];
  const float* Wv   = (const float*)d_in[5];
  const float* Wo   = (const float*)d_in[6];
  const float* rmss = (const float*)d_in[7];
  const float* Wc   = (const float*)d_in[8];
  const float* bc   = (const float*)d_in[9];
  float* out = (float*)d_out;

  char* ws = (char*)d_ws;
  const size_t MB = 1u << 20;
  bf16*  xb  = (bf16*)(ws);               // 0..8MB    (B,S,E) bf16
  bf16*  Wqb = (bf16*)(ws + 8  * MB);     // Wq,Wk,Wv,Wo contiguous 8..16MB
  bf16*  Wkb = (bf16*)(ws + 10 * MB);
  bf16*  Wvb = (bf16*)(ws + 12 * MB);
  bf16*  Wob = (bf16*)(ws + 14 * MB);
  bf16*  Qb  = (bf16*)(ws + 16 * MB);     // (B,H,S,D); K at +4M el; V^T at +8M el
  bf16*  Kb  = (bf16*)(ws + 24 * MB);
  bf16*  Vt  = (bf16*)(ws + 32 * MB);
  bf16*  Oa  = (bf16*)(ws);               // reuse x region
  float* tmp = (float*)(ws + 16 * MB);    // reuse Q/K region
  float* mod = (float*)(ws + 40 * MB);

  const int NX = NB * NS * NE;

  mod_kernel<<<16, 256, 0, stream>>>(cond, Wc, bc, mod);

  cvt_kernel<<<NX / 2048, 256, 0, stream>>>(x, xb, NX);
  cvt4_kernel<<<2048, 256, 0, stream>>>(Wq, Wk, Wv, Wo, Wqb);

  // fused QKV projection: N = 3072
  gemm128<0><<<dim3(32, 24), 256, 0, stream>>>(xb, Wqb, Wkb, Wvb, Qb, NE);

  attn_kernel<<<2048, 256, 0, stream>>>(Qb, Kb, Vt, Oa);

  // O projection -> f32 tmp
  gemm128<1><<<dim3(32, 8), 256, 0, stream>>>(Oa, Wob, nullptr, nullptr, tmp, NE);

  norm_kernel<<<NB * NS, 256, 0, stream>>>(tmp, rmss, mod, out);
}

// Round 10
// 209.899 us; speedup vs baseline: 1.2746x; 1.2746x over previous
//
#include <hip/hip_runtime.h>
#include <hip/hip_bf16.h>
#include <stdint.h>

typedef __bf16 bf16;
typedef __bf16 bf16x8 __attribute__((ext_vector_type(8)));
typedef float  f32x4  __attribute__((ext_vector_type(4)));

#define NB 2
#define NS 2048
#define NE 1024
#define NH 16
#define ND 64
#define NC 256

// async global->LDS, 16B per lane, wave-uniform LDS base + lane*16
__device__ __forceinline__ void gload16(void* lds, const void* g) {
  __builtin_amdgcn_global_load_lds(
      (const __attribute__((address_space(1))) void*)g,
      (__attribute__((address_space(3))) void*)lds, 16, 0, 0);
}

template <int CTRL>
__device__ __forceinline__ float rowror_max(float x) {
  int xi = __builtin_bit_cast(int, x);
  int yi = __builtin_amdgcn_update_dpp(xi, xi, CTRL, 0xF, 0xF, false);
  return fmaxf(x, __builtin_bit_cast(float, yi));
}

__device__ __forceinline__ float rowmax16(float x) {
  x = rowror_max<0x121>(x);   // row_ror:1
  x = rowror_max<0x122>(x);   // row_ror:2
  x = rowror_max<0x124>(x);   // row_ror:4
  x = rowror_max<0x128>(x);   // row_ror:8
  return x;
}

// ---------------------------------------------------------------------------
// f32 -> bf16 conversion (vectorized, 8 elems/thread)
// ---------------------------------------------------------------------------
__global__ __launch_bounds__(256) void cvt_kernel(
    const float* __restrict__ src, bf16* __restrict__ dst, int n) {
  int i = (blockIdx.x * 256 + threadIdx.x) * 8;
  if (i >= n) return;
  float4 a = ((const float4*)(src + i))[0];
  float4 b = ((const float4*)(src + i))[1];
  bf16x8 o;
  o[0] = (bf16)a.x; o[1] = (bf16)a.y; o[2] = (bf16)a.z; o[3] = (bf16)a.w;
  o[4] = (bf16)b.x; o[5] = (bf16)b.y; o[6] = (bf16)b.z; o[7] = (bf16)b.w;
  *(bf16x8*)(dst + i) = o;
}

// fused conversion of the four 1024x1024 weights into one contiguous dst
__global__ __launch_bounds__(256) void cvt4_kernel(
    const float* __restrict__ s0, const float* __restrict__ s1,
    const float* __restrict__ s2, const float* __restrict__ s3,
    bf16* __restrict__ dst) {
  int seg = blockIdx.x >> 9;
  int blk = blockIdx.x & 511;
  const float* s = (seg == 0) ? s0 : (seg == 1) ? s1 : (seg == 2) ? s2 : s3;
  int i = (blk * 256 + threadIdx.x) * 8;
  float4 a = ((const float4*)(s + i))[0];
  float4 b = ((const float4*)(s + i))[1];
  bf16x8 o;
  o[0] = (bf16)a.x; o[1] = (bf16)a.y; o[2] = (bf16)a.z; o[3] = (bf16)a.w;
  o[4] = (bf16)b.x; o[5] = (bf16)b.y; o[6] = (bf16)b.z; o[7] = (bf16)b.w;
  *(bf16x8*)(dst + seg * 1048576 + i) = o;
}

// ---------------------------------------------------------------------------
// mod = silu(conditioning) @ Wc^T + bc   -> f32 (B, 2E)
// ---------------------------------------------------------------------------
__global__ __launch_bounds__(256) void mod_kernel(
    const float* __restrict__ cond, const float* __restrict__ Wc,
    const float* __restrict__ bc, float* __restrict__ mod) {
  __shared__ float scond[NC];
  int b  = blockIdx.x >> 3;
  int j0 = (blockIdx.x & 7) * 256;
  float c = cond[b * NC + threadIdx.x];
  scond[threadIdx.x] = c / (1.f + __expf(-c));
  __syncthreads();
  int j = j0 + threadIdx.x;
  float acc = bc[j];
  const float* wrow = Wc + (size_t)j * NC;
  for (int cc = 0; cc < NC; ++cc) acc += scond[cc] * wrow[cc];
  mod[b * 2 * NE + j] = acc;
}

// ---------------------------------------------------------------------------
// 128x128 LDS-staged NT GEMM (m97 structure). K multiple of 32.
// MODE 0: fused QKV (N=3072, weight picked by n>>10), scatter epilogue.
// MODE 1: O-projection, f32 row-major out, N=1024.
// ---------------------------------------------------------------------------
template<int MODE>
__global__ __launch_bounds__(256) void gemm128(
    const bf16* __restrict__ A, const bf16* __restrict__ W0,
    const bf16* __restrict__ W1, const bf16* __restrict__ W2,
    void* __restrict__ out, int K) {
  __shared__ bf16 As[128 * 32];
  __shared__ bf16 Bs[128 * 32];
  const int t = threadIdx.x, w = t >> 6, l = t & 63;
  const int lr = l & 15, lg = l >> 4;
  const int wm = w >> 1, wn = w & 1;
  const int m0 = blockIdx.x * 128;
  const int ng = blockIdx.y * 128;

  const bf16* Bw;
  if (MODE == 0) {
    const bf16* Ws[3] = {W0, W1, W2};
    Bw = Ws[ng >> 10] + (size_t)(ng & 1023) * K;
  } else {
    Bw = W0 + (size_t)ng * K;
  }

  f32x4 acc[4][4];
#pragma unroll
  for (int i = 0; i < 4; ++i)
#pragma unroll
    for (int j = 0; j < 4; ++j) acc[i][j] = (f32x4){0.f, 0.f, 0.f, 0.f};

  const int srow = (l >> 2);
  const int scol = (l & 3) * 8;

  for (int kt = 0; kt < K; kt += 32) {
#pragma unroll
    for (int r = 0; r < 2; ++r) {
      int cc = w * 2 + r;
      int row = cc * 16 + srow;
      gload16((char*)As + cc * 1024, A  + (size_t)(m0 + row) * K + kt + scol);
      gload16((char*)Bs + cc * 1024, Bw + (size_t)row        * K + kt + scol);
    }
    __syncthreads();
    bf16x8 af[4], bfr[4];
#pragma unroll
    for (int i = 0; i < 4; ++i) {
      af[i]  = *(const bf16x8*)(As + (wm * 64 + i * 16 + lr) * 32 + lg * 8);
      bfr[i] = *(const bf16x8*)(Bs + (wn * 64 + i * 16 + lr) * 32 + lg * 8);
    }
#pragma unroll
    for (int i = 0; i < 4; ++i)
#pragma unroll
      for (int j = 0; j < 4; ++j)
        acc[i][j] = __builtin_amdgcn_mfma_f32_16x16x32_bf16(af[i], bfr[j], acc[i][j], 0, 0, 0);
    if (kt + 32 < K) __syncthreads();
  }

#pragma unroll
  for (int i = 0; i < 4; ++i) {
#pragma unroll
    for (int j = 0; j < 4; ++j) {
#pragma unroll
      for (int r = 0; r < 4; ++r) {
        int row = m0 + wm * 64 + i * 16 + lg * 4 + r;
        int col = ng + wn * 64 + j * 16 + lr;
        float v = acc[i][j][r];
        if (MODE == 1) {
          ((float*)out)[(size_t)row * NE + col] = v;
        } else {
          int b = row >> 11, s = row & 2047;
          int wi = col >> 10, nc = col & 1023;
          int h = nc >> 6, d = nc & 63;
          size_t idx;
          if (wi == 2)  // V^T: (B,H,D,S)
            idx = 8388608u + (((size_t)(b * NH + h)) * ND + d) * NS + s;
          else          // Q or K: (B,H,S,D)
            idx = (size_t)wi * 4194304u + (((size_t)(b * NH + h)) * NS + s) * ND + d;
          ((bf16*)out)[idx] = (bf16)v;
        }
      }
    }
  }
}

// ---------------------------------------------------------------------------
// Flash attention, causal (r5 structure + XCD head-locality swizzle).
// Q,K (B,H,S,D), V^T (B,H,D,S). Out (B,S,E) bf16.
// Wave = 16 q-rows; each wave does the complementary pair (tp, 127-tp).
// Flat grid of 512 blocks: bid&7 = XCD (HW round-robin), each XCD's 64
// resident blocks serve 4 heads -> 2MB K/V live in its 4MB L2 (r8-proven:
// FETCH 120MB -> 12MB). Row-sum via ones-MFMA; row-max via DPP.
// ---------------------------------------------------------------------------
__global__ __launch_bounds__(256) void attn_kernel(
    const bf16* __restrict__ Q, const bf16* __restrict__ Km,
    const bf16* __restrict__ Vt, bf16* __restrict__ O) {
  __shared__ bf16 pbuf[4][16][72];   // per-wave P^T buffer, padded
  const int l = threadIdx.x & 63, w = threadIdx.x >> 6;
  const int lr = l & 15, lg = l >> 4;
  const int bid = blockIdx.x;
  const int xcd = bid & 7, slot = bid >> 3;   // slot 0..63
  const int bh = xcd * 4 + (slot >> 4);       // 4 heads per XCD
  const int b = bh >> 4, h = bh & 15;
  const int tp = (slot & 15) * 4 + w;         // 0..63

  const bf16* Qb = Q  + (size_t)bh * NS * ND;
  const bf16* Kb = Km + (size_t)bh * NS * ND;
  const bf16* Vb = Vt + (size_t)bh * ND * NS;

  bf16x8 ones;
#pragma unroll
  for (int i = 0; i < 8; ++i) ones[i] = (bf16)1.0f;

  const float c = 0.125f * 1.44269504089f;   // scale * log2(e)

  for (int pass = 0; pass < 2; ++pass) {
    const int qbase = (pass ? (127 - tp) : tp) * 16;

    bf16x8 qf0 = *(const bf16x8*)(Qb + (size_t)(qbase + lr) * ND + lg * 8);
    bf16x8 qf1 = *(const bf16x8*)(Qb + (size_t)(qbase + lr) * ND + 32 + lg * 8);

    f32x4 o[4], osum;
#pragma unroll
    for (int dt = 0; dt < 4; ++dt) o[dt] = (f32x4){0.f, 0.f, 0.f, 0.f};
    osum = (f32x4){0.f, 0.f, 0.f, 0.f};
    float mrow[4];
    int qr[4];
#pragma unroll
    for (int r = 0; r < 4; ++r) { mrow[r] = -1e30f; qr[r] = qbase + lg * 4 + r; }

    for (int kv0 = 0; kv0 < qbase + 16; kv0 += 64) {
      // ---- QK^T : 16 q-rows x 64 kv ----
      f32x4 s[4];
#pragma unroll
      for (int nt = 0; nt < 4; ++nt) {
        const bf16* kr = Kb + (size_t)(kv0 + nt * 16 + lr) * ND + lg * 8;
        bf16x8 k0 = *(const bf16x8*)kr;
        bf16x8 k1 = *(const bf16x8*)(kr + 32);
        f32x4 z = (f32x4){0.f, 0.f, 0.f, 0.f};
        z = __builtin_amdgcn_mfma_f32_16x16x32_bf16(qf0, k0, z, 0, 0, 0);
        z = __builtin_amdgcn_mfma_f32_16x16x32_bf16(qf1, k1, z, 0, 0, 0);
        s[nt] = z;
      }
      // ---- scale (log2 domain) + causal mask + row max ----
      const bool edge = (kv0 + 63 > qbase);
      float pm[4];
#pragma unroll
      for (int r = 0; r < 4; ++r) pm[r] = -1e30f;
#pragma unroll
      for (int nt = 0; nt < 4; ++nt) {
        f32x4 v = s[nt] * c;
#pragma unroll
        for (int r = 0; r < 4; ++r) {
          if (edge && (kv0 + nt * 16 + lr > qr[r])) v[r] = -1e30f;
          pm[r] = fmaxf(pm[r], v[r]);
        }
        s[nt] = v;
      }
#pragma unroll
      for (int r = 0; r < 4; ++r) pm[r] = rowmax16(pm[r]);
      // ---- online rescale ----
      float al[4];
#pragma unroll
      for (int r = 0; r < 4; ++r) {
        float nm = fmaxf(mrow[r], pm[r]);
        al[r] = exp2f(mrow[r] - nm);
        mrow[r] = nm;
      }
#pragma unroll
      for (int dt = 0; dt < 4; ++dt)
#pragma unroll
        for (int r = 0; r < 4; ++r) o[dt][r] *= al[r];
#pragma unroll
      for (int r = 0; r < 4; ++r) osum[r] *= al[r];
      // ---- P = exp2(s - m), transpose via wave-private LDS ----
#pragma unroll
      for (int nt = 0; nt < 4; ++nt)
#pragma unroll
        for (int r = 0; r < 4; ++r)
          pbuf[w][lg * 4 + r][nt * 16 + lr] = (bf16)exp2f(s[nt][r] - mrow[r]);
      asm volatile("s_waitcnt lgkmcnt(0)" ::: "memory");
      __builtin_amdgcn_sched_barrier(0);
      bf16x8 pa0 = *(const bf16x8*)(&pbuf[w][lr][lg * 8]);
      bf16x8 pa1 = *(const bf16x8*)(&pbuf[w][lr][32 + lg * 8]);
      // ---- row-sum via ones-operand MFMA ----
      osum = __builtin_amdgcn_mfma_f32_16x16x32_bf16(pa0, ones, osum, 0, 0, 0);
      osum = __builtin_amdgcn_mfma_f32_16x16x32_bf16(pa1, ones, osum, 0, 0, 0);
      // ---- PV ----
#pragma unroll
      for (int dt = 0; dt < 4; ++dt) {
        const bf16* vr = Vb + (size_t)(dt * 16 + lr) * NS + kv0 + lg * 8;
        bf16x8 v0 = *(const bf16x8*)vr;
        bf16x8 v1 = *(const bf16x8*)(vr + 32);
        o[dt] = __builtin_amdgcn_mfma_f32_16x16x32_bf16(pa0, v0, o[dt], 0, 0, 0);
        o[dt] = __builtin_amdgcn_mfma_f32_16x16x32_bf16(pa1, v1, o[dt], 0, 0, 0);
      }
      __builtin_amdgcn_sched_barrier(0);
    }

    float rl[4];
#pragma unroll
    for (int r = 0; r < 4; ++r) rl[r] = 1.f / osum[r];
#pragma unroll
    for (int dt = 0; dt < 4; ++dt)
#pragma unroll
      for (int r = 0; r < 4; ++r)
        O[((size_t)(b * NS) + qr[r]) * NE + h * ND + dt * 16 + lr] =
            (bf16)(o[dt][r] * rl[r]);
  }
}

// ---------------------------------------------------------------------------
// RMSNorm + FiLM
// ---------------------------------------------------------------------------
__global__ __launch_bounds__(256) void norm_kernel(
    const float* __restrict__ tmp, const float* __restrict__ rms_scale,
    const float* __restrict__ mod, float* __restrict__ out) {
  int row = blockIdx.x;
  int b = row >> 11;
  const float* trow = tmp + (size_t)row * NE;
  float4 v = ((const float4*)trow)[threadIdx.x];
  float vv[4] = {v.x, v.y, v.z, v.w};
  float ss = vv[0]*vv[0] + vv[1]*vv[1] + vv[2]*vv[2] + vv[3]*vv[3];
#pragma unroll
  for (int mk = 1; mk < 64; mk <<= 1) ss += __shfl_xor(ss, mk, 64);
  __shared__ float sred[4];
  if ((threadIdx.x & 63) == 0) sred[threadIdx.x >> 6] = ss;
  __syncthreads();
  float tot = sred[0] + sred[1] + sred[2] + sred[3];
  float rinv = rsqrtf(tot * (1.f / NE) + 1e-6f);
  const float* modb = mod + b * 2 * NE;
#pragma unroll
  for (int j = 0; j < 4; ++j) {
    int e = threadIdx.x * 4 + j;
    float xn = vv[j] * rinv * rms_scale[e];
    xn = xn * (1.f + modb[NE + e]) + modb[e];
    out[(size_t)row * NE + e] = xn;
  }
}

// ---------------------------------------------------------------------------
extern "C" void kernel_launch(void* const* d_in, const int* in_sizes, int n_in,
                              void* d_out, int out_size, void* d_ws, size_t ws_size,
                              hipStream_t stream) {
  const float* x    = (const float*)d_in[0];
  const float* cond = (const float*)d_in[2];
  const float* Wq   = (const float*)d_in[3];
  const float* Wk   = (const float*)d_in[4];
  const float* Wv   = (const float*)d_in[5];
  const float* Wo   = (const float*)d_in[6];
  const float* rmss = (const float*)d_in[7];
  const float* Wc   = (const float*)d_in[8];
  const float* bc   = (const float*)d_in[9];
  float* out = (float*)d_out;

  char* ws = (char*)d_ws;
  const size_t MB = 1u << 20;
  bf16*  xb  = (bf16*)(ws);               // 0..8MB    (B,S,E) bf16
  bf16*  Wqb = (bf16*)(ws + 8  * MB);     // Wq,Wk,Wv,Wo contiguous 8..16MB
  bf16*  Wkb = (bf16*)(ws + 10 * MB);
  bf16*  Wvb = (bf16*)(ws + 12 * MB);
  bf16*  Wob = (bf16*)(ws + 14 * MB);
  bf16*  Qb  = (bf16*)(ws + 16 * MB);     // (B,H,S,D); K at +4M el; V^T at +8M el
  bf16*  Kb  = (bf16*)(ws + 24 * MB);
  bf16*  Vt  = (bf16*)(ws + 32 * MB);
  bf16*  Oa  = (bf16*)(ws);               // reuse x region
  float* tmp = (float*)(ws + 16 * MB);    // reuse Q/K region
  float* mod = (float*)(ws + 40 * MB);

  const int NX = NB * NS * NE;

  mod_kernel<<<16, 256, 0, stream>>>(cond, Wc, bc, mod);

  cvt_kernel<<<NX / 2048, 256, 0, stream>>>(x, xb, NX);
  cvt4_kernel<<<2048, 256, 0, stream>>>(Wq, Wk, Wv, Wo, Wqb);

  // fused QKV projection: N = 3072
  gemm128<0><<<dim3(32, 24), 256, 0, stream>>>(xb, Wqb, Wkb, Wvb, Qb, NE);

  attn_kernel<<<512, 256, 0, stream>>>(Qb, Kb, Vt, Oa);

  // O projection -> f32 tmp
  gemm128<1><<<dim3(32, 8), 256, 0, stream>>>(Oa, Wob, nullptr, nullptr, tmp, NE);

  norm_kernel<<<NB * NS, 256, 0, stream>>>(tmp, rmss, mod, out);
}

// Round 11
// 208.094 us; speedup vs baseline: 1.2857x; 1.0087x over previous
//
#include <hip/hip_runtime.h>
#include <hip/hip_bf16.h>
#include <stdint.h>

typedef __bf16 bf16;
typedef __bf16 bf16x8 __attribute__((ext_vector_type(8)));
typedef float  f32x4  __attribute__((ext_vector_type(4)));

#define NB 2
#define NS 2048
#define NE 1024
#define NH 16
#define ND 64
#define NC 256

#define EXP2(x) __builtin_amdgcn_exp2f(x)

// async global->LDS, 16B per lane, wave-uniform LDS base + lane*16
__device__ __forceinline__ void gload16(void* lds, const void* g) {
  __builtin_amdgcn_global_load_lds(
      (const __attribute__((address_space(1))) void*)g,
      (__attribute__((address_space(3))) void*)lds, 16, 0, 0);
}

template <int CTRL>
__device__ __forceinline__ float rowror_max(float x) {
  int xi = __builtin_bit_cast(int, x);
  int yi = __builtin_amdgcn_update_dpp(xi, xi, CTRL, 0xF, 0xF, false);
  return fmaxf(x, __builtin_bit_cast(float, yi));
}

__device__ __forceinline__ float rowmax16(float x) {
  x = rowror_max<0x121>(x);   // row_ror:1
  x = rowror_max<0x122>(x);   // row_ror:2
  x = rowror_max<0x124>(x);   // row_ror:4
  x = rowror_max<0x128>(x);   // row_ror:8
  return x;
}

// ---------------------------------------------------------------------------
// f32 -> bf16 conversion (vectorized, 8 elems/thread)
// ---------------------------------------------------------------------------
__global__ __launch_bounds__(256) void cvt_kernel(
    const float* __restrict__ src, bf16* __restrict__ dst, int n) {
  int i = (blockIdx.x * 256 + threadIdx.x) * 8;
  if (i >= n) return;
  float4 a = ((const float4*)(src + i))[0];
  float4 b = ((const float4*)(src + i))[1];
  bf16x8 o;
  o[0] = (bf16)a.x; o[1] = (bf16)a.y; o[2] = (bf16)a.z; o[3] = (bf16)a.w;
  o[4] = (bf16)b.x; o[5] = (bf16)b.y; o[6] = (bf16)b.z; o[7] = (bf16)b.w;
  *(bf16x8*)(dst + i) = o;
}

// fused conversion of the four 1024x1024 weights into one contiguous dst
__global__ __launch_bounds__(256) void cvt4_kernel(
    const float* __restrict__ s0, const float* __restrict__ s1,
    const float* __restrict__ s2, const float* __restrict__ s3,
    bf16* __restrict__ dst) {
  int seg = blockIdx.x >> 9;
  int blk = blockIdx.x & 511;
  const float* s = (seg == 0) ? s0 : (seg == 1) ? s1 : (seg == 2) ? s2 : s3;
  int i = (blk * 256 + threadIdx.x) * 8;
  float4 a = ((const float4*)(s + i))[0];
  float4 b = ((const float4*)(s + i))[1];
  bf16x8 o;
  o[0] = (bf16)a.x; o[1] = (bf16)a.y; o[2] = (bf16)a.z; o[3] = (bf16)a.w;
  o[4] = (bf16)b.x; o[5] = (bf16)b.y; o[6] = (bf16)b.z; o[7] = (bf16)b.w;
  *(bf16x8*)(dst + seg * 1048576 + i) = o;
}

// ---------------------------------------------------------------------------
// mod = silu(conditioning) @ Wc^T + bc   -> f32 (B, 2E)
// ---------------------------------------------------------------------------
__global__ __launch_bounds__(256) void mod_kernel(
    const float* __restrict__ cond, const float* __restrict__ Wc,
    const float* __restrict__ bc, float* __restrict__ mod) {
  __shared__ float scond[NC];
  int b  = blockIdx.x >> 3;
  int j0 = (blockIdx.x & 7) * 256;
  float c = cond[b * NC + threadIdx.x];
  scond[threadIdx.x] = c / (1.f + __expf(-c));
  __syncthreads();
  int j = j0 + threadIdx.x;
  float acc = bc[j];
  const float* wrow = Wc + (size_t)j * NC;
  for (int cc = 0; cc < NC; ++cc) acc += scond[cc] * wrow[cc];
  mod[b * 2 * NE + j] = acc;
}

// ---------------------------------------------------------------------------
// 128x128 LDS-staged NT GEMM (m97 structure). K multiple of 32.
// MODE 0: fused QKV (N=3072, weight picked by n>>10), scatter epilogue.
//         Q output pre-scaled by 0.125*log2(e) for the attention kernel.
// MODE 1: O-projection, f32 row-major out, N=1024.
// ---------------------------------------------------------------------------
template<int MODE>
__global__ __launch_bounds__(256) void gemm128(
    const bf16* __restrict__ A, const bf16* __restrict__ W0,
    const bf16* __restrict__ W1, const bf16* __restrict__ W2,
    void* __restrict__ out, int K) {
  __shared__ bf16 As[128 * 32];
  __shared__ bf16 Bs[128 * 32];
  const int t = threadIdx.x, w = t >> 6, l = t & 63;
  const int lr = l & 15, lg = l >> 4;
  const int wm = w >> 1, wn = w & 1;
  const int m0 = blockIdx.x * 128;
  const int ng = blockIdx.y * 128;

  const bf16* Bw;
  if (MODE == 0) {
    const bf16* Ws[3] = {W0, W1, W2};
    Bw = Ws[ng >> 10] + (size_t)(ng & 1023) * K;
  } else {
    Bw = W0 + (size_t)ng * K;
  }

  f32x4 acc[4][4];
#pragma unroll
  for (int i = 0; i < 4; ++i)
#pragma unroll
    for (int j = 0; j < 4; ++j) acc[i][j] = (f32x4){0.f, 0.f, 0.f, 0.f};

  const int srow = (l >> 2);
  const int scol = (l & 3) * 8;

  for (int kt = 0; kt < K; kt += 32) {
#pragma unroll
    for (int r = 0; r < 2; ++r) {
      int cc = w * 2 + r;
      int row = cc * 16 + srow;
      gload16((char*)As + cc * 1024, A  + (size_t)(m0 + row) * K + kt + scol);
      gload16((char*)Bs + cc * 1024, Bw + (size_t)row        * K + kt + scol);
    }
    __syncthreads();
    bf16x8 af[4], bfr[4];
#pragma unroll
    for (int i = 0; i < 4; ++i) {
      af[i]  = *(const bf16x8*)(As + (wm * 64 + i * 16 + lr) * 32 + lg * 8);
      bfr[i] = *(const bf16x8*)(Bs + (wn * 64 + i * 16 + lr) * 32 + lg * 8);
    }
#pragma unroll
    for (int i = 0; i < 4; ++i)
#pragma unroll
      for (int j = 0; j < 4; ++j)
        acc[i][j] = __builtin_amdgcn_mfma_f32_16x16x32_bf16(af[i], bfr[j], acc[i][j], 0, 0, 0);
    if (kt + 32 < K) __syncthreads();
  }

#pragma unroll
  for (int i = 0; i < 4; ++i) {
#pragma unroll
    for (int j = 0; j < 4; ++j) {
#pragma unroll
      for (int r = 0; r < 4; ++r) {
        int row = m0 + wm * 64 + i * 16 + lg * 4 + r;
        int col = ng + wn * 64 + j * 16 + lr;
        float v = acc[i][j][r];
        if (MODE == 1) {
          ((float*)out)[(size_t)row * NE + col] = v;
        } else {
          int b = row >> 11, s = row & 2047;
          int wi = col >> 10, nc = col & 1023;
          int h = nc >> 6, d = nc & 63;
          size_t idx;
          if (wi == 0) v *= 0.180336880f;   // pre-fold softmax scale*log2e into Q
          if (wi == 2)  // V^T: (B,H,D,S)
            idx = 8388608u + (((size_t)(b * NH + h)) * ND + d) * NS + s;
          else          // Q or K: (B,H,S,D)
            idx = (size_t)wi * 4194304u + (((size_t)(b * NH + h)) * NS + s) * ND + d;
          ((bf16*)out)[idx] = (bf16)v;
        }
      }
    }
  }
}

// ---------------------------------------------------------------------------
// Flash attention, causal (r10 structure + fast exp2 + K prefetch + V-hoist).
// Q pre-scaled by 0.125*log2e. Q,K (B,H,S,D), V^T (B,H,D,S). Out bf16.
// Wave = 16 q-rows; complementary pair (tp, 127-tp); XCD head-locality
// swizzle (FETCH 120->12MB, r10-proven). Softmax in exp2 domain with
// v_exp_f32 directly (the compiler's exp2f libcall was ~300 extra chained
// VALU ops/iter without -ffast-math — the r5..r10 130us plateau).
// ---------------------------------------------------------------------------
__global__ __launch_bounds__(256) void attn_kernel(
    const bf16* __restrict__ Q, const bf16* __restrict__ Km,
    const bf16* __restrict__ Vt, bf16* __restrict__ O) {
  __shared__ bf16 pbuf[4][16][72];   // per-wave P^T buffer, padded
  const int l = threadIdx.x & 63, w = threadIdx.x >> 6;
  const int lr = l & 15, lg = l >> 4;
  const int bid = blockIdx.x;
  const int xcd = bid & 7, slot = bid >> 3;   // slot 0..63
  const int bh = xcd * 4 + (slot >> 4);       // 4 heads per XCD
  const int b = bh >> 4, h = bh & 15;
  const int tp = (slot & 15) * 4 + w;         // 0..63

  const bf16* Qb = Q  + (size_t)bh * NS * ND;
  const bf16* Kb = Km + (size_t)bh * NS * ND;
  const bf16* Vb = Vt + (size_t)bh * ND * NS;

  bf16x8 ones;
#pragma unroll
  for (int i = 0; i < 8; ++i) ones[i] = (bf16)1.0f;

  for (int pass = 0; pass < 2; ++pass) {
    const int qbase = (pass ? (127 - tp) : tp) * 16;

    bf16x8 qf0 = *(const bf16x8*)(Qb + (size_t)(qbase + lr) * ND + lg * 8);
    bf16x8 qf1 = *(const bf16x8*)(Qb + (size_t)(qbase + lr) * ND + 32 + lg * 8);

    f32x4 o[4], osum;
#pragma unroll
    for (int dt = 0; dt < 4; ++dt) o[dt] = (f32x4){0.f, 0.f, 0.f, 0.f};
    osum = (f32x4){0.f, 0.f, 0.f, 0.f};
    float mrow[4];
    int qr[4];
#pragma unroll
    for (int r = 0; r < 4; ++r) { mrow[r] = -1e30f; qr[r] = qbase + lg * 4 + r; }

    const int niter = (qbase + 16 + 63) >> 6;

    auto loadK = [&](bf16x8 (&k0)[4], bf16x8 (&k1)[4], int it) {
      const int kv0 = it * 64;
#pragma unroll
      for (int nt = 0; nt < 4; ++nt) {
        const bf16* kr = Kb + (size_t)(kv0 + nt * 16 + lr) * ND + lg * 8;
        k0[nt] = *(const bf16x8*)kr;
        k1[nt] = *(const bf16x8*)(kr + 32);
      }
    };

    auto step = [&](const bf16x8 (&kc0)[4], const bf16x8 (&kc1)[4], int it) {
      const int kv0 = it * 64;
      // V loads at iteration top: latency hides under QK^T + softmax
      bf16x8 v0[4], v1[4];
#pragma unroll
      for (int dt = 0; dt < 4; ++dt) {
        const bf16* vr = Vb + (size_t)(dt * 16 + lr) * NS + kv0 + lg * 8;
        v0[dt] = *(const bf16x8*)vr;
        v1[dt] = *(const bf16x8*)(vr + 32);
      }
      // ---- QK^T (Q pre-scaled) ----
      f32x4 s[4];
#pragma unroll
      for (int nt = 0; nt < 4; ++nt) {
        f32x4 z = (f32x4){0.f, 0.f, 0.f, 0.f};
        z = __builtin_amdgcn_mfma_f32_16x16x32_bf16(qf0, kc0[nt], z, 0, 0, 0);
        z = __builtin_amdgcn_mfma_f32_16x16x32_bf16(qf1, kc1[nt], z, 0, 0, 0);
        s[nt] = z;
      }
      // ---- causal mask + row max ----
      const bool edge = (kv0 + 63 > qbase);
      float pm[4];
#pragma unroll
      for (int r = 0; r < 4; ++r) pm[r] = -1e30f;
#pragma unroll
      for (int nt = 0; nt < 4; ++nt) {
        f32x4 v = s[nt];
#pragma unroll
        for (int r = 0; r < 4; ++r) {
          if (edge && (kv0 + nt * 16 + lr > qr[r])) v[r] = -1e30f;
          pm[r] = fmaxf(pm[r], v[r]);
        }
        s[nt] = v;
      }
#pragma unroll
      for (int r = 0; r < 4; ++r) pm[r] = rowmax16(pm[r]);
      // ---- online rescale ----
      float al[4];
#pragma unroll
      for (int r = 0; r < 4; ++r) {
        float nm = fmaxf(mrow[r], pm[r]);
        al[r] = EXP2(mrow[r] - nm);
        mrow[r] = nm;
      }
#pragma unroll
      for (int dt = 0; dt < 4; ++dt)
#pragma unroll
        for (int r = 0; r < 4; ++r) o[dt][r] *= al[r];
#pragma unroll
      for (int r = 0; r < 4; ++r) osum[r] *= al[r];
      // ---- P = exp2(s - m), transpose via wave-private LDS ----
#pragma unroll
      for (int nt = 0; nt < 4; ++nt)
#pragma unroll
        for (int r = 0; r < 4; ++r)
          pbuf[w][lg * 4 + r][nt * 16 + lr] = (bf16)EXP2(s[nt][r] - mrow[r]);
      asm volatile("s_waitcnt lgkmcnt(0)" ::: "memory");
      __builtin_amdgcn_sched_barrier(0);
      bf16x8 pa0 = *(const bf16x8*)(&pbuf[w][lr][lg * 8]);
      bf16x8 pa1 = *(const bf16x8*)(&pbuf[w][lr][32 + lg * 8]);
      // ---- row-sum via ones-operand MFMA ----
      osum = __builtin_amdgcn_mfma_f32_16x16x32_bf16(pa0, ones, osum, 0, 0, 0);
      osum = __builtin_amdgcn_mfma_f32_16x16x32_bf16(pa1, ones, osum, 0, 0, 0);
      // ---- PV ----
#pragma unroll
      for (int dt = 0; dt < 4; ++dt) {
        o[dt] = __builtin_amdgcn_mfma_f32_16x16x32_bf16(pa0, v0[dt], o[dt], 0, 0, 0);
        o[dt] = __builtin_amdgcn_mfma_f32_16x16x32_bf16(pa1, v1[dt], o[dt], 0, 0, 0);
      }
    };

    // K double-set software pipeline (no trailing sched_barrier: let the
    // compiler overlap next-iter loads with this iter's compute)
    bf16x8 ka0[4], ka1[4], kb0[4], kb1[4];
    loadK(ka0, ka1, 0);
    int it = 0;
    while (true) {
      if (it + 1 < niter) loadK(kb0, kb1, it + 1);
      step(ka0, ka1, it);
      if (++it >= niter) break;
      if (it + 1 < niter) loadK(ka0, ka1, it + 1);
      step(kb0, kb1, it);
      if (++it >= niter) break;
    }

    float rl[4];
#pragma unroll
    for (int r = 0; r < 4; ++r) rl[r] = 1.f / osum[r];
#pragma unroll
    for (int dt = 0; dt < 4; ++dt)
#pragma unroll
      for (int r = 0; r < 4; ++r)
        O[((size_t)(b * NS) + qr[r]) * NE + h * ND + dt * 16 + lr] =
            (bf16)(o[dt][r] * rl[r]);
  }
}

// ---------------------------------------------------------------------------
// RMSNorm + FiLM
// ---------------------------------------------------------------------------
__global__ __launch_bounds__(256) void norm_kernel(
    const float* __restrict__ tmp, const float* __restrict__ rms_scale,
    const float* __restrict__ mod, float* __restrict__ out) {
  int row = blockIdx.x;
  int b = row >> 11;
  const float* trow = tmp + (size_t)row * NE;
  float4 v = ((const float4*)trow)[threadIdx.x];
  float vv[4] = {v.x, v.y, v.z, v.w};
  float ss = vv[0]*vv[0] + vv[1]*vv[1] + vv[2]*vv[2] + vv[3]*vv[3];
#pragma unroll
  for (int mk = 1; mk < 64; mk <<= 1) ss += __shfl_xor(ss, mk, 64);
  __shared__ float sred[4];
  if ((threadIdx.x & 63) == 0) sred[threadIdx.x >> 6] = ss;
  __syncthreads();
  float tot = sred[0] + sred[1] + sred[2] + sred[3];
  float rinv = rsqrtf(tot * (1.f / NE) + 1e-6f);
  const float* modb = mod + b * 2 * NE;
#pragma unroll
  for (int j = 0; j < 4; ++j) {
    int e = threadIdx.x * 4 + j;
    float xn = vv[j] * rinv * rms_scale[e];
    xn = xn * (1.f + modb[NE + e]) + modb[e];
    out[(size_t)row * NE + e] = xn;
  }
}

// ---------------------------------------------------------------------------
extern "C" void kernel_launch(void* const* d_in, const int* in_sizes, int n_in,
                              void* d_out, int out_size, void* d_ws, size_t ws_size,
                              hipStream_t stream) {
  const float* x    = (const float*)d_in[0];
  const float* cond = (const float*)d_in[2];
  const float* Wq   = (const float*)d_in[3];
  const float* Wk   = (const float*)d_in[4];
  const float* Wv   = (const float*)d_in[5];
  const float* Wo   = (const float*)d_in[6];
  const float* rmss = (const float*)d_in[7];
  const float* Wc   = (const float*)d_in[8];
  const float* bc   = (const float*)d_in[9];
  float* out = (float*)d_out;

  char* ws = (char*)d_ws;
  const size_t MB = 1u << 20;
  bf16*  xb  = (bf16*)(ws);               // 0..8MB    (B,S,E) bf16
  bf16*  Wqb = (bf16*)(ws + 8  * MB);     // Wq,Wk,Wv,Wo contiguous 8..16MB
  bf16*  Wkb = (bf16*)(ws + 10 * MB);
  bf16*  Wvb = (bf16*)(ws + 12 * MB);
  bf16*  Wob = (bf16*)(ws + 14 * MB);
  bf16*  Qb  = (bf16*)(ws + 16 * MB);     // (B,H,S,D); K at +4M el; V^T at +8M el
  bf16*  Kb  = (bf16*)(ws + 24 * MB);
  bf16*  Vt  = (bf16*)(ws + 32 * MB);
  bf16*  Oa  = (bf16*)(ws);               // reuse x region
  float* tmp = (float*)(ws + 16 * MB);    // reuse Q/K region
  float* mod = (float*)(ws + 40 * MB);

  const int NX = NB * NS * NE;

  mod_kernel<<<16, 256, 0, stream>>>(cond, Wc, bc, mod);

  cvt_kernel<<<NX / 2048, 256, 0, stream>>>(x, xb, NX);
  cvt4_kernel<<<2048, 256, 0, stream>>>(Wq, Wk, Wv, Wo, Wqb);

  // fused QKV projection: N = 3072
  gemm128<0><<<dim3(32, 24), 256, 0, stream>>>(xb, Wqb, Wkb, Wvb, Qb, NE);

  attn_kernel<<<512, 256, 0, stream>>>(Qb, Kb, Vt, Oa);

  // O projection -> f32 tmp
  gemm128<1><<<dim3(32, 8), 256, 0, stream>>>(Oa, Wob, nullptr, nullptr, tmp, NE);

  norm_kernel<<<NB * NS, 256, 0, stream>>>(tmp, rmss, mod, out);
}